// Round 11
// baseline (7713.203 us; speedup 1.0000x reference)
//
#include <hip/hip_runtime.h>
#include <hip/hip_bf16.h>

#define SEQ   2048
#define NBATCH 64
#define HID   512
#define KDIM  512

typedef float f32x4  __attribute__((ext_vector_type(4)));
typedef short bf16x8 __attribute__((ext_vector_type(8)));

__device__ __forceinline__ unsigned short f2bf(float f) {
  union { float f; unsigned int u; } v; v.f = f;
  unsigned int r = v.u + 0x7FFFu + ((v.u >> 16) & 1u);
  return (unsigned short)(r >> 16);
}

__device__ __forceinline__ f32x4 mfma16(bf16x8 a, bf16x8 b, f32x4 c) {
  return __builtin_amdgcn_mfma_f32_16x16x32_bf16(a, b, c, 0, 0, 0);
}

// Repack W [H=512 rows n][K=512 cols k] (row-major fp32) into MFMA-fragment-major bf16:
// element index = ((kf*32 + cfg)*64 + lane)*8 + e  with n = cfg*16 + (lane&15),
// k = kf*32 + (lane>>4)*8 + e.
__global__ void prep_wfrag(const float* __restrict__ W, unsigned short* __restrict__ dst) {
  int tid = blockIdx.x * blockDim.x + threadIdx.x;   // 0 .. 262143
  int e   = tid & 7;
  int l   = (tid >> 3) & 63;
  int cfg = (tid >> 9) & 31;
  int kf  = tid >> 14;
  int n = cfg * 16 + (l & 15);
  int k = kf * 32 + (l >> 4) * 8 + e;
  dst[tid] = f2bf(W[n * KDIM + k]);
}

__global__ void prep_bsum(const float* __restrict__ a, const float* __restrict__ b,
                          float* __restrict__ out) {
  int j = threadIdx.x;
  if (j < HID) out[j] = a[j] + b[j];
}

// Phase 1: xp = X * W_ih^T + (b_ih + b_hh), NATURAL layout [s*64+b][n] fp32.
__global__ __launch_bounds__(512) void rnn_xproj(
    const float* __restrict__ X,
    const uint4* __restrict__ BW,
    const float* __restrict__ bsum,
    float* __restrict__ out) {
  const int tid = threadIdx.x, w = tid >> 6, l = tid & 63;
  const int g = l >> 4, lr = l & 15;
  const int rowbase = blockIdx.x * 64 + (w >> 2) * 32;
  const int colw = (w & 3) * 128;

  f32x4 acc[2][8];
  #pragma unroll
  for (int cf = 0; cf < 8; ++cf) {
    float bv = bsum[colw + cf * 16 + lr];
    f32x4 z = {bv, bv, bv, bv};
    acc[0][cf] = z; acc[1][cf] = z;
  }

  #pragma unroll 1
  for (int kc = 0; kc < 16; ++kc) {
    const int kb = kc * 32 + g * 8;
    bf16x8 afr[2];
    #pragma unroll
    for (int ai = 0; ai < 2; ++ai) {
      const float* src = X + (size_t)(rowbase + ai * 16 + lr) * KDIM + kb;
      float4 lo = *reinterpret_cast<const float4*>(src);
      float4 hi = *reinterpret_cast<const float4*>(src + 4);
      bf16x8 a;
      a[0] = (short)f2bf(lo.x); a[1] = (short)f2bf(lo.y);
      a[2] = (short)f2bf(lo.z); a[3] = (short)f2bf(lo.w);
      a[4] = (short)f2bf(hi.x); a[5] = (short)f2bf(hi.y);
      a[6] = (short)f2bf(hi.z); a[7] = (short)f2bf(hi.w);
      afr[ai] = a;
    }
    #pragma unroll
    for (int cf = 0; cf < 8; ++cf) {
      const int cfg = (w & 3) * 8 + cf;
      uint4 braw = BW[(kc * 32 + cfg) * 64 + l];
      bf16x8 b = __builtin_bit_cast(bf16x8, braw);
      acc[0][cf] = mfma16(afr[0], b, acc[0][cf]);
      acc[1][cf] = mfma16(afr[1], b, acc[1][cf]);
    }
  }

  #pragma unroll
  for (int ai = 0; ai < 2; ++ai) {
    #pragma unroll
    for (int cf = 0; cf < 8; ++cf) {
      const int col = colw + cf * 16 + lr;
      #pragma unroll
      for (int r = 0; r < 4; ++r) {
        const int row = rowbase + ai * 16 + g * 4 + r;
        out[(size_t)row * HID + col] = acc[ai][cf][r];
      }
    }
  }
}

// Phase 2: sequential scan, orientation-swapped: D[n_out][b] = sum_k W[n_out][k] h[b][k].
// 4 blocks x 512 threads (8 waves, 2/SIMD). Wave w owns mf = w*4..w*4+3.
// LDS (163840 B):
//   [0,131072):      W_hh A-frags kf0-3 (linear, frag f=kf*32+mf_g at f*1024)
//   [131072,147456): h buf0 in B-FRAGMENT layout (frag kf at kf*1024, elem (l,e) at l*16+e*2)
//   [147456,163840): h buf1
// W_hh kf4..15 in 192 regs.  All LDS accesses conflict-free / 2-way.
// r11 change vs r10: WAVE-PARITY PHASE STAGGER (clean — no setprio, no sched
// pinning): even waves run [kf0-3 LDS-A phase][kf4-15 reg-A phase], odd waves
// run the reverse. At any instant ~half the CU's waves are in the LDS-light
// reg phase (pumping MFMA) while the other half burst LDS -> the two pipes
// overlap instead of serializing (r10 counters showed sum, not max).
__global__ __launch_bounds__(512, 2) void rnn_scan(
    const uint4* __restrict__ BW,   // W_hh frag-major bf16 (16384 frags)
    float* __restrict__ xo) {       // d_out: xp in (natural), h out (natural)
  extern __shared__ char smem[];
  const int tid = threadIdx.x, w = tid >> 6, l = tid & 63;
  const int g = l >> 4, lr = l & 15;
  const int bg = blockIdx.x;

  // stage W_hh kf0-3 (128 KB, linear)
  {
    uint4* lb = reinterpret_cast<uint4*>(smem);
    #pragma unroll
    for (int i = 0; i < 16; ++i) lb[i * 512 + tid] = BW[i * 512 + tid];
  }
  // zero h buf1 (step 0 reads RD=16384; zeros valid in any layout)
  {
    float* hz = reinterpret_cast<float*>(smem + 147456);
    #pragma unroll
    for (int i = 0; i < 8; ++i) hz[i * 512 + tid] = 0.f;
  }
  // register A-frags kf4..15 for this wave's 4 m-frags (static indices only)
  bf16x8 ar[12][4];
  #pragma unroll
  for (int kf = 0; kf < 12; ++kf)
    #pragma unroll
    for (int mf = 0; mf < 4; ++mf)
      ar[kf][mf] = __builtin_bit_cast(bf16x8,
          BW[((kf + 4) * 32 + (w * 4 + mf)) * 64 + l]);
  __syncthreads();

  // per-lane constants
  const int hoff = l * 16;                        // hb read offset within frag
  const int apre = (w * 4) * 1024 + l * 16;       // + kf*32768 + mf*1024
  const int hwb  = (w * 2) * 1024 + (g >> 1) * 256 + (g & 1) * 8 + lr * 16;
  float* xrow0 = xo + ((size_t)bg * 16 + lr) * HID + (size_t)(w * 4) * 16 + g * 4;

#define HB(kf, RD) (*reinterpret_cast<const bf16x8*>(                            \
    smem + 131072 + (RD) + (kf) * 1024 + hoff))
#define AF(kf, mf) (*reinterpret_cast<const bf16x8*>(                            \
    smem + (kf) * 32768 + apre + (mf) * 1024))

  // prologue: xp(0) -> regs; kf0 A-quad -> regs
  f32x4 xv[4];
  #pragma unroll
  for (int mf = 0; mf < 4; ++mf)
    xv[mf] = *reinterpret_cast<const f32x4*>(xrow0 + mf * 16);
  bf16x8 pa0 = AF(0, 0), pa1 = AF(0, 1), pa2 = AF(0, 2), pa3 = AF(0, 3);

// LDS-A phase: kf0 (A from pa regs) + kf1-3 (A from LDS); 16 MFMA, 16 b128
#define LDSA_PHASE(RD)                                                            \
    {                                                                             \
      bf16x8 hb = HB(0, RD);                                                      \
      acc[0] = mfma16(pa0, hb, acc[0]);                                           \
      acc[1] = mfma16(pa1, hb, acc[1]);                                           \
      acc[2] = mfma16(pa2, hb, acc[2]);                                           \
      acc[3] = mfma16(pa3, hb, acc[3]);                                           \
    }                                                                             \
    _Pragma("unroll")                                                             \
    for (int kf = 1; kf < 4; ++kf) {                                              \
      bf16x8 hb = HB(kf, RD);                                                     \
      const char* ab = smem + kf * 32768 + apre;                                  \
      acc[0] = mfma16(*reinterpret_cast<const bf16x8*>(ab       ), hb, acc[0]);   \
      acc[1] = mfma16(*reinterpret_cast<const bf16x8*>(ab + 1024), hb, acc[1]);   \
      acc[2] = mfma16(*reinterpret_cast<const bf16x8*>(ab + 2048), hb, acc[2]);   \
      acc[3] = mfma16(*reinterpret_cast<const bf16x8*>(ab + 3072), hb, acc[3]);   \
    }

// reg-A phase: kf4-15; 48 MFMA, 12 b128
#define REGA_PHASE(RD)                                                            \
    _Pragma("unroll")                                                             \
    for (int kf = 0; kf < 12; ++kf) {                                             \
      bf16x8 hb = HB(kf + 4, RD);                                                 \
      acc[0] = mfma16(ar[kf][0], hb, acc[0]);                                     \
      acc[1] = mfma16(ar[kf][1], hb, acc[1]);                                     \
      acc[2] = mfma16(ar[kf][2], hb, acc[2]);                                     \
      acc[3] = mfma16(ar[kf][3], hb, acc[3]);                                     \
    }

#define SCAN_STEP(S, RD, WR)                                                      \
  {                                                                               \
    const int s = (S);                                                            \
    f32x4 acc[4];                                                                 \
    _Pragma("unroll")                                                             \
    for (int mf = 0; mf < 4; ++mf) acc[mf] = xv[mf];                              \
    { /* prefetch xp(s+1) (consumed next step; clamp harmless at tail) */         \
      const float* xn = xrow0 + (size_t)(s + 1 < SEQ ? s + 1 : s) * (64 * HID);   \
      _Pragma("unroll")                                                           \
      for (int mf = 0; mf < 4; ++mf)                                              \
        xv[mf] = *reinterpret_cast<const f32x4*>(xn + mf * 16);                   \
    }                                                                             \
    /* wave-parity stagger: opposite phase order per parity (fp-reorder only) */  \
    if (w & 1) { REGA_PHASE(RD) LDSA_PHASE(RD) }                                  \
    else       { LDSA_PHASE(RD) REGA_PHASE(RD) }                                  \
    /* epilogue: tanh, f32x4 out, frag-layout h write (uint2, 2-way free) */      \
    float* orow = xrow0 + (size_t)s * (64 * HID);                                 \
    _Pragma("unroll")                                                             \
    for (int mf = 0; mf < 4; ++mf) {                                              \
      f32x4 hv;                                                                   \
      _Pragma("unroll")                                                           \
      for (int r = 0; r < 4; ++r) {                                               \
        const float pre = acc[mf][r];                                             \
        hv[r] = 1.0f - 2.0f * __builtin_amdgcn_rcpf(1.0f + __expf(2.0f * pre));   \
      }                                                                           \
      *reinterpret_cast<f32x4*>(orow + mf * 16) = hv;                             \
      uint2 hp;                                                                   \
      hp.x = (unsigned)f2bf(hv[0]) | ((unsigned)f2bf(hv[1]) << 16);               \
      hp.y = (unsigned)f2bf(hv[2]) | ((unsigned)f2bf(hv[3]) << 16);               \
      *reinterpret_cast<uint2*>(smem + 131072 + (WR) + hwb +                      \
          (mf >> 1) * 1024 + (mf & 1) * 512) = hp;                                \
    }                                                                             \
    /* prefetch NEXT step's kf0 A-quad (static W, no hazard) into the drain */    \
    pa0 = AF(0, 0); pa1 = AF(0, 1); pa2 = AF(0, 2); pa3 = AF(0, 3);               \
    asm volatile("s_waitcnt lgkmcnt(0)\n\ts_barrier" ::: "memory");               \
  }

  #pragma unroll 1
  for (int s2 = 0; s2 < SEQ; s2 += 2) {
    SCAN_STEP(s2,     16384, 0)      // even step: read buf1, write buf0
    SCAN_STEP(s2 + 1, 0,     16384)  // odd step:  read buf0, write buf1
  }
#undef SCAN_STEP
#undef LDSA_PHASE
#undef REGA_PHASE
#undef HB
#undef AF
}

extern "C" void kernel_launch(void* const* d_in, const int* in_sizes, int n_in,
                              void* d_out, int out_size, void* d_ws, size_t ws_size,
                              hipStream_t stream) {
  (void)in_sizes; (void)n_in; (void)out_size;
  const float* X   = (const float*)d_in[0];
  const float* Wih = (const float*)d_in[1];
  const float* Whh = (const float*)d_in[2];
  const float* bih = (const float*)d_in[3];
  const float* bhh = (const float*)d_in[4];
  float* out = (float*)d_out;

  unsigned short* wihf = (unsigned short*)d_ws;              // 512 KB
  unsigned short* whhf = wihf + 262144;                      // 512 KB
  float* bsum = (float*)(whhf + 262144);                     // 2 KB
  if (ws_size < (size_t)(2 * 524288 + 2048)) return;

  prep_wfrag<<<1024, 256, 0, stream>>>(Wih, wihf);
  prep_wfrag<<<1024, 256, 0, stream>>>(Whh, whhf);
  prep_bsum<<<1, 512, 0, stream>>>(bih, bhh, bsum);

  rnn_xproj<<<2048, 512, 0, stream>>>(X, (const uint4*)wihf, bsum, out);

  hipFuncSetAttribute(reinterpret_cast<const void*>(rnn_scan),
                      hipFuncAttributeMaxDynamicSharedMemorySize, 163840);
  rnn_scan<<<4, 512, 163840, stream>>>((const uint4*)whhf, out);
}

// Round 12
// 4912.260 us; speedup vs baseline: 1.5702x; 1.5702x over previous
//
#include <hip/hip_runtime.h>
#include <hip/hip_bf16.h>

#define SEQ   2048
#define NBATCH 64
#define HID   512
#define KDIM  512

typedef float f32x4  __attribute__((ext_vector_type(4)));
typedef short bf16x8 __attribute__((ext_vector_type(8)));

__device__ __forceinline__ unsigned short f2bf(float f) {
  union { float f; unsigned int u; } v; v.f = f;
  unsigned int r = v.u + 0x7FFFu + ((v.u >> 16) & 1u);
  return (unsigned short)(r >> 16);
}

__device__ __forceinline__ f32x4 mfma16(bf16x8 a, bf16x8 b, f32x4 c) {
  return __builtin_amdgcn_mfma_f32_16x16x32_bf16(a, b, c, 0, 0, 0);
}

// Repack W [H=512 rows n][K=512 cols k] (row-major fp32) into MFMA-fragment-major bf16:
// element index = ((kf*32 + cfg)*64 + lane)*8 + e  with n = cfg*16 + (lane&15),
// k = kf*32 + (lane>>4)*8 + e.
__global__ void prep_wfrag(const float* __restrict__ W, unsigned short* __restrict__ dst) {
  int tid = blockIdx.x * blockDim.x + threadIdx.x;   // 0 .. 262143
  int e   = tid & 7;
  int l   = (tid >> 3) & 63;
  int cfg = (tid >> 9) & 31;
  int kf  = tid >> 14;
  int n = cfg * 16 + (l & 15);
  int k = kf * 32 + (l >> 4) * 8 + e;
  dst[tid] = f2bf(W[n * KDIM + k]);
}

__global__ void prep_bsum(const float* __restrict__ a, const float* __restrict__ b,
                          float* __restrict__ out) {
  int j = threadIdx.x;
  if (j < HID) out[j] = a[j] + b[j];
}

// Phase 1: xp = X * W_ih^T + (b_ih + b_hh), NATURAL layout [s*64+b][n] fp32.
__global__ __launch_bounds__(512) void rnn_xproj(
    const float* __restrict__ X,
    const uint4* __restrict__ BW,
    const float* __restrict__ bsum,
    float* __restrict__ out) {
  const int tid = threadIdx.x, w = tid >> 6, l = tid & 63;
  const int g = l >> 4, lr = l & 15;
  const int rowbase = blockIdx.x * 64 + (w >> 2) * 32;
  const int colw = (w & 3) * 128;

  f32x4 acc[2][8];
  #pragma unroll
  for (int cf = 0; cf < 8; ++cf) {
    float bv = bsum[colw + cf * 16 + lr];
    f32x4 z = {bv, bv, bv, bv};
    acc[0][cf] = z; acc[1][cf] = z;
  }

  #pragma unroll 1
  for (int kc = 0; kc < 16; ++kc) {
    const int kb = kc * 32 + g * 8;
    bf16x8 afr[2];
    #pragma unroll
    for (int ai = 0; ai < 2; ++ai) {
      const float* src = X + (size_t)(rowbase + ai * 16 + lr) * KDIM + kb;
      float4 lo = *reinterpret_cast<const float4*>(src);
      float4 hi = *reinterpret_cast<const float4*>(src + 4);
      bf16x8 a;
      a[0] = (short)f2bf(lo.x); a[1] = (short)f2bf(lo.y);
      a[2] = (short)f2bf(lo.z); a[3] = (short)f2bf(lo.w);
      a[4] = (short)f2bf(hi.x); a[5] = (short)f2bf(hi.y);
      a[6] = (short)f2bf(hi.z); a[7] = (short)f2bf(hi.w);
      afr[ai] = a;
    }
    #pragma unroll
    for (int cf = 0; cf < 8; ++cf) {
      const int cfg = (w & 3) * 8 + cf;
      uint4 braw = BW[(kc * 32 + cfg) * 64 + l];
      bf16x8 b = __builtin_bit_cast(bf16x8, braw);
      acc[0][cf] = mfma16(afr[0], b, acc[0][cf]);
      acc[1][cf] = mfma16(afr[1], b, acc[1][cf]);
    }
  }

  #pragma unroll
  for (int ai = 0; ai < 2; ++ai) {
    #pragma unroll
    for (int cf = 0; cf < 8; ++cf) {
      const int col = colw + cf * 16 + lr;
      #pragma unroll
      for (int r = 0; r < 4; ++r) {
        const int row = rowbase + ai * 16 + g * 4 + r;
        out[(size_t)row * HID + col] = acc[ai][cf][r];
      }
    }
  }
}

// Phase 2: sequential scan, orientation-swapped: D[n_out][b] = sum_k W[n_out][k] h[b][k].
// 4 blocks x 512 threads (8 waves, 2/SIMD), LOCKSTEP schedule (r10 anchor).
// LDS (163840 B):
//   [0,131072):      W_hh A-frags kf0-3 (linear, frag f=kf*32+mf_g at f*1024)
//   [131072,147456): h buf0, B-FRAGMENT layout (frag kf at kf*1024, (l,e) at l*16+e*2)
//   [147456,163840): h buf1
// W_hh kf4..15 in 192 regs.  r12 changes vs r10:
//  (1) xp loaded MID-step (after LDS-A phase, consumed at epilogue) -> 16 regs
//      free during the read-burst phase (read-ahead headroom);
//  (2) pa prefetch covers kf0 AND kf1 (8 quads in drain) -> in-step A-reads 12->8;
//  (3) counted barrier: h-writes -> sched_barrier(0) -> 8 pa reads ->
//      lgkmcnt(8)+s_barrier (writes drained, pa reads ride across);
//  (4) v_cvt_pk_bf16_f32 epilogue pack.
__global__ __launch_bounds__(512, 2) void rnn_scan(
    const uint4* __restrict__ BW,   // W_hh frag-major bf16 (16384 frags)
    float* __restrict__ xo) {       // d_out: xp in (natural), h out (natural)
  extern __shared__ char smem[];
  const int tid = threadIdx.x, w = tid >> 6, l = tid & 63;
  const int g = l >> 4, lr = l & 15;
  const int bg = blockIdx.x;

  // stage W_hh kf0-3 (128 KB, linear)
  {
    uint4* lb = reinterpret_cast<uint4*>(smem);
    #pragma unroll
    for (int i = 0; i < 16; ++i) lb[i * 512 + tid] = BW[i * 512 + tid];
  }
  // zero h buf1 (step 0 reads RD=16384)
  {
    float* hz = reinterpret_cast<float*>(smem + 147456);
    #pragma unroll
    for (int i = 0; i < 8; ++i) hz[i * 512 + tid] = 0.f;
  }
  // register A-frags kf4..15 for this wave's 4 m-frags (static indices only)
  bf16x8 ar[12][4];
  #pragma unroll
  for (int kf = 0; kf < 12; ++kf)
    #pragma unroll
    for (int mf = 0; mf < 4; ++mf)
      ar[kf][mf] = __builtin_bit_cast(bf16x8,
          BW[((kf + 4) * 32 + (w * 4 + mf)) * 64 + l]);
  __syncthreads();

  // per-lane constants
  const int hoff = l * 16;                        // hb read offset within frag
  const int apre = (w * 4) * 1024 + l * 16;       // + kf*32768 + mf*1024
  const int hwb  = (w * 2) * 1024 + (g >> 1) * 256 + (g & 1) * 8 + lr * 16;
  float* xrow0 = xo + ((size_t)bg * 16 + lr) * HID + (size_t)(w * 4) * 16 + g * 4;

#define HB(kf, RD) (*reinterpret_cast<const bf16x8*>(                            \
    smem + 131072 + (RD) + (kf) * 1024 + hoff))
#define AF(kf, mf) (*reinterpret_cast<const bf16x8*>(                            \
    smem + (kf) * 32768 + apre + (mf) * 1024))

  // prologue: pa quads for kf0 + kf1
  bf16x8 pa0 = AF(0, 0), pa1 = AF(0, 1), pa2 = AF(0, 2), pa3 = AF(0, 3);
  bf16x8 pa4 = AF(1, 0), pa5 = AF(1, 1), pa6 = AF(1, 2), pa7 = AF(1, 3);

#define SCAN_STEP(S, RD, WR)                                                      \
  {                                                                               \
    const int s = (S);                                                            \
    f32x4 acc0 = {0,0,0,0}, acc1 = {0,0,0,0}, acc2 = {0,0,0,0}, acc3 = {0,0,0,0}; \
    /* kf0, kf1: A from pa regs (prefetched in prev drain) */                     \
    {                                                                             \
      bf16x8 hb = HB(0, RD);                                                      \
      acc0 = mfma16(pa0, hb, acc0); acc1 = mfma16(pa1, hb, acc1);                 \
      acc2 = mfma16(pa2, hb, acc2); acc3 = mfma16(pa3, hb, acc3);                 \
    }                                                                             \
    {                                                                             \
      bf16x8 hb = HB(1, RD);                                                      \
      acc0 = mfma16(pa4, hb, acc0); acc1 = mfma16(pa5, hb, acc1);                 \
      acc2 = mfma16(pa6, hb, acc2); acc3 = mfma16(pa7, hb, acc3);                 \
    }                                                                             \
    /* kf2-3: A from LDS */                                                       \
    _Pragma("unroll")                                                             \
    for (int kf = 2; kf < 4; ++kf) {                                              \
      bf16x8 hb = HB(kf, RD);                                                     \
      const char* ab = smem + kf * 32768 + apre;                                  \
      acc0 = mfma16(*reinterpret_cast<const bf16x8*>(ab       ), hb, acc0);       \
      acc1 = mfma16(*reinterpret_cast<const bf16x8*>(ab + 1024), hb, acc1);       \
      acc2 = mfma16(*reinterpret_cast<const bf16x8*>(ab + 2048), hb, acc2);       \
      acc3 = mfma16(*reinterpret_cast<const bf16x8*>(ab + 3072), hb, acc3);       \
    }                                                                             \
    /* xp(s) for CURRENT step: ~2400 cyc of cover to epilogue */                  \
    const float* xrs = xrow0 + (size_t)s * (64 * HID);                            \
    f32x4 xt0 = *reinterpret_cast<const f32x4*>(xrs);                             \
    f32x4 xt1 = *reinterpret_cast<const f32x4*>(xrs + 16);                        \
    f32x4 xt2 = *reinterpret_cast<const f32x4*>(xrs + 32);                        \
    f32x4 xt3 = *reinterpret_cast<const f32x4*>(xrs + 48);                        \
    /* kf4-15: reg A */                                                           \
    _Pragma("unroll")                                                             \
    for (int kf = 0; kf < 12; ++kf) {                                             \
      bf16x8 hb = HB(kf + 4, RD);                                                 \
      acc0 = mfma16(ar[kf][0], hb, acc0);                                         \
      acc1 = mfma16(ar[kf][1], hb, acc1);                                         \
      acc2 = mfma16(ar[kf][2], hb, acc2);                                         \
      acc3 = mfma16(ar[kf][3], hb, acc3);                                         \
    }                                                                             \
    /* epilogue: tanh, f32x4 out, cvt_pk pack + uint2 h write */                  \
    float* orow = xrow0 + (size_t)s * (64 * HID);                                 \
    f32x4 hv0, hv1, hv2, hv3;                                                     \
    _Pragma("unroll")                                                             \
    for (int r = 0; r < 4; ++r) {                                                 \
      hv0[r] = 1.0f - 2.0f * __builtin_amdgcn_rcpf(1.0f + __expf(2.0f * (acc0[r] + xt0[r]))); \
      hv1[r] = 1.0f - 2.0f * __builtin_amdgcn_rcpf(1.0f + __expf(2.0f * (acc1[r] + xt1[r]))); \
      hv2[r] = 1.0f - 2.0f * __builtin_amdgcn_rcpf(1.0f + __expf(2.0f * (acc2[r] + xt2[r]))); \
      hv3[r] = 1.0f - 2.0f * __builtin_amdgcn_rcpf(1.0f + __expf(2.0f * (acc3[r] + xt3[r]))); \
    }                                                                             \
    *reinterpret_cast<f32x4*>(orow)      = hv0;                                   \
    *reinterpret_cast<f32x4*>(orow + 16) = hv1;                                   \
    *reinterpret_cast<f32x4*>(orow + 32) = hv2;                                   \
    *reinterpret_cast<f32x4*>(orow + 48) = hv3;                                   \
    uint2 hp;                                                                     \
    asm("v_cvt_pk_bf16_f32 %0, %1, %2" : "=v"(hp.x) : "v"(hv0[0]), "v"(hv0[1])); \
    asm("v_cvt_pk_bf16_f32 %0, %1, %2" : "=v"(hp.y) : "v"(hv0[2]), "v"(hv0[3])); \
    *reinterpret_cast<uint2*>(smem + 131072 + (WR) + hwb)        = hp;            \
    asm("v_cvt_pk_bf16_f32 %0, %1, %2" : "=v"(hp.x) : "v"(hv1[0]), "v"(hv1[1])); \
    asm("v_cvt_pk_bf16_f32 %0, %1, %2" : "=v"(hp.y) : "v"(hv1[2]), "v"(hv1[3])); \
    *reinterpret_cast<uint2*>(smem + 131072 + (WR) + hwb + 512)  = hp;            \
    asm("v_cvt_pk_bf16_f32 %0, %1, %2" : "=v"(hp.x) : "v"(hv2[0]), "v"(hv2[1])); \
    asm("v_cvt_pk_bf16_f32 %0, %1, %2" : "=v"(hp.y) : "v"(hv2[2]), "v"(hv2[3])); \
    *reinterpret_cast<uint2*>(smem + 131072 + (WR) + hwb + 1024) = hp;            \
    asm("v_cvt_pk_bf16_f32 %0, %1, %2" : "=v"(hp.x) : "v"(hv3[0]), "v"(hv3[1])); \
    asm("v_cvt_pk_bf16_f32 %0, %1, %2" : "=v"(hp.y) : "v"(hv3[2]), "v"(hv3[3])); \
    *reinterpret_cast<uint2*>(smem + 131072 + (WR) + hwb + 1536) = hp;            \
    /* pin order: h-writes above, pa reads below (prevents read-hoist race) */    \
    __builtin_amdgcn_sched_barrier(0);                                            \
    pa0 = AF(0, 0); pa1 = AF(0, 1); pa2 = AF(0, 2); pa3 = AF(0, 3);               \
    pa4 = AF(1, 0); pa5 = AF(1, 1); pa6 = AF(1, 2); pa7 = AF(1, 3);               \
    /* counted: drain the 4 h-writes (older, in-order), keep 8 pa reads live */   \
    asm volatile("s_waitcnt lgkmcnt(8)\n\ts_barrier" ::: "memory");               \
  }

  #pragma unroll 1
  for (int s2 = 0; s2 < SEQ; s2 += 2) {
    SCAN_STEP(s2,     16384, 0)      // even step: read buf1, write buf0
    SCAN_STEP(s2 + 1, 0,     16384)  // odd step:  read buf0, write buf1
  }
#undef SCAN_STEP
#undef HB
#undef AF
}

extern "C" void kernel_launch(void* const* d_in, const int* in_sizes, int n_in,
                              void* d_out, int out_size, void* d_ws, size_t ws_size,
                              hipStream_t stream) {
  (void)in_sizes; (void)n_in; (void)out_size;
  const float* X   = (const float*)d_in[0];
  const float* Wih = (const float*)d_in[1];
  const float* Whh = (const float*)d_in[2];
  const float* bih = (const float*)d_in[3];
  const float* bhh = (const float*)d_in[4];
  float* out = (float*)d_out;

  unsigned short* wihf = (unsigned short*)d_ws;              // 512 KB
  unsigned short* whhf = wihf + 262144;                      // 512 KB
  float* bsum = (float*)(whhf + 262144);                     // 2 KB
  if (ws_size < (size_t)(2 * 524288 + 2048)) return;

  prep_wfrag<<<1024, 256, 0, stream>>>(Wih, wihf);
  prep_wfrag<<<1024, 256, 0, stream>>>(Whh, whhf);
  prep_bsum<<<1, 512, 0, stream>>>(bih, bhh, bsum);

  rnn_xproj<<<2048, 512, 0, stream>>>(X, (const uint4*)wihf, bsum, out);

  hipFuncSetAttribute(reinterpret_cast<const void*>(rnn_scan),
                      hipFuncAttributeMaxDynamicSharedMemorySize, 163840);
  rnn_scan<<<4, 512, 163840, stream>>>((const uint4*)whhf, out);
}

// Round 13
// 4835.471 us; speedup vs baseline: 1.5951x; 1.0159x over previous
//
#include <hip/hip_runtime.h>
#include <hip/hip_bf16.h>

#define SEQ   2048
#define NBATCH 64
#define HID   512
#define KDIM  512

typedef float f32x4  __attribute__((ext_vector_type(4)));
typedef short bf16x8 __attribute__((ext_vector_type(8)));

__device__ __forceinline__ unsigned short f2bf(float f) {
  union { float f; unsigned int u; } v; v.f = f;
  unsigned int r = v.u + 0x7FFFu + ((v.u >> 16) & 1u);
  return (unsigned short)(r >> 16);
}

__device__ __forceinline__ f32x4 mfma16(bf16x8 a, bf16x8 b, f32x4 c) {
  return __builtin_amdgcn_mfma_f32_16x16x32_bf16(a, b, c, 0, 0, 0);
}

// Repack W [H=512 rows n][K=512 cols k] (row-major fp32) into MFMA-fragment-major bf16:
// element index = ((kf*32 + cfg)*64 + lane)*8 + e  with n = cfg*16 + (lane&15),
// k = kf*32 + (lane>>4)*8 + e.
__global__ void prep_wfrag(const float* __restrict__ W, unsigned short* __restrict__ dst) {
  int tid = blockIdx.x * blockDim.x + threadIdx.x;   // 0 .. 262143
  int e   = tid & 7;
  int l   = (tid >> 3) & 63;
  int cfg = (tid >> 9) & 31;
  int kf  = tid >> 14;
  int n = cfg * 16 + (l & 15);
  int k = kf * 32 + (l >> 4) * 8 + e;
  dst[tid] = f2bf(W[n * KDIM + k]);
}

__global__ void prep_bsum(const float* __restrict__ a, const float* __restrict__ b,
                          float* __restrict__ out) {
  int j = threadIdx.x;
  if (j < HID) out[j] = a[j] + b[j];
}

// Phase 1: xp = X * W_ih^T + (b_ih + b_hh), NATURAL layout [s*64+b][n] fp32.
__global__ __launch_bounds__(512) void rnn_xproj(
    const float* __restrict__ X,
    const uint4* __restrict__ BW,
    const float* __restrict__ bsum,
    float* __restrict__ out) {
  const int tid = threadIdx.x, w = tid >> 6, l = tid & 63;
  const int g = l >> 4, lr = l & 15;
  const int rowbase = blockIdx.x * 64 + (w >> 2) * 32;
  const int colw = (w & 3) * 128;

  f32x4 acc[2][8];
  #pragma unroll
  for (int cf = 0; cf < 8; ++cf) {
    float bv = bsum[colw + cf * 16 + lr];
    f32x4 z = {bv, bv, bv, bv};
    acc[0][cf] = z; acc[1][cf] = z;
  }

  #pragma unroll 1
  for (int kc = 0; kc < 16; ++kc) {
    const int kb = kc * 32 + g * 8;
    bf16x8 afr[2];
    #pragma unroll
    for (int ai = 0; ai < 2; ++ai) {
      const float* src = X + (size_t)(rowbase + ai * 16 + lr) * KDIM + kb;
      float4 lo = *reinterpret_cast<const float4*>(src);
      float4 hi = *reinterpret_cast<const float4*>(src + 4);
      bf16x8 a;
      a[0] = (short)f2bf(lo.x); a[1] = (short)f2bf(lo.y);
      a[2] = (short)f2bf(lo.z); a[3] = (short)f2bf(lo.w);
      a[4] = (short)f2bf(hi.x); a[5] = (short)f2bf(hi.y);
      a[6] = (short)f2bf(hi.z); a[7] = (short)f2bf(hi.w);
      afr[ai] = a;
    }
    #pragma unroll
    for (int cf = 0; cf < 8; ++cf) {
      const int cfg = (w & 3) * 8 + cf;
      uint4 braw = BW[(kc * 32 + cfg) * 64 + l];
      bf16x8 b = __builtin_bit_cast(bf16x8, braw);
      acc[0][cf] = mfma16(afr[0], b, acc[0][cf]);
      acc[1][cf] = mfma16(afr[1], b, acc[1][cf]);
    }
  }

  #pragma unroll
  for (int ai = 0; ai < 2; ++ai) {
    #pragma unroll
    for (int cf = 0; cf < 8; ++cf) {
      const int col = colw + cf * 16 + lr;
      #pragma unroll
      for (int r = 0; r < 4; ++r) {
        const int row = rowbase + ai * 16 + g * 4 + r;
        out[(size_t)row * HID + col] = acc[ai][cf][r];
      }
    }
  }
}

// Phase 2: sequential scan, orientation-swapped: D[n_out][b] = sum_k W[n_out][k] h[b][k].
// 4 blocks x 512 threads (8 waves, 2/SIMD), LOCKSTEP schedule (r12 anchor).
// LDS (163840 B):
//   [0,131072):      W_hh A-frags kf0-3 (linear, frag f=kf*32+mf_g at f*1024)
//   [131072,147456): h buf0, B-FRAGMENT layout (frag kf at kf*1024, (l,e) at l*16+e*2)
//   [147456,163840): h buf1
// W_hh kf4..15 in 192 regs.  r13 change vs r12:
//   DEPTH-2 hb SOFTWARE PIPELINE: two hb frags in flight (hA/hB); each kf phase
//   consumes one and issues the read for kf+2 (read-ahead ~180 cyc > ~120 cyc
//   LDS latency -> waits become ~free). +4 net registers, no reordering.
__global__ __launch_bounds__(512, 2) void rnn_scan(
    const uint4* __restrict__ BW,   // W_hh frag-major bf16 (16384 frags)
    float* __restrict__ xo) {       // d_out: xp in (natural), h out (natural)
  extern __shared__ char smem[];
  const int tid = threadIdx.x, w = tid >> 6, l = tid & 63;
  const int g = l >> 4, lr = l & 15;
  const int bg = blockIdx.x;

  // stage W_hh kf0-3 (128 KB, linear)
  {
    uint4* lb = reinterpret_cast<uint4*>(smem);
    #pragma unroll
    for (int i = 0; i < 16; ++i) lb[i * 512 + tid] = BW[i * 512 + tid];
  }
  // zero h buf1 (step 0 reads RD=16384)
  {
    float* hz = reinterpret_cast<float*>(smem + 147456);
    #pragma unroll
    for (int i = 0; i < 8; ++i) hz[i * 512 + tid] = 0.f;
  }
  // register A-frags kf4..15 for this wave's 4 m-frags (static indices only)
  bf16x8 ar[12][4];
  #pragma unroll
  for (int kf = 0; kf < 12; ++kf)
    #pragma unroll
    for (int mf = 0; mf < 4; ++mf)
      ar[kf][mf] = __builtin_bit_cast(bf16x8,
          BW[((kf + 4) * 32 + (w * 4 + mf)) * 64 + l]);
  __syncthreads();

  // per-lane constants
  const int hoff = l * 16;                        // hb read offset within frag
  const int apre = (w * 4) * 1024 + l * 16;       // + kf*32768 + mf*1024
  const int hwb  = (w * 2) * 1024 + (g >> 1) * 256 + (g & 1) * 8 + lr * 16;
  float* xrow0 = xo + ((size_t)bg * 16 + lr) * HID + (size_t)(w * 4) * 16 + g * 4;

#define HB(kf, RD) (*reinterpret_cast<const bf16x8*>(                            \
    smem + 131072 + (RD) + (kf) * 1024 + hoff))
#define AF(kf, mf) (*reinterpret_cast<const bf16x8*>(                            \
    smem + (kf) * 32768 + apre + (mf) * 1024))
// 4 MFMAs with reg-A frags ar[i]
#define M4A(i, h)                                                                \
    acc0 = mfma16(ar[i][0], h, acc0); acc1 = mfma16(ar[i][1], h, acc1);          \
    acc2 = mfma16(ar[i][2], h, acc2); acc3 = mfma16(ar[i][3], h, acc3);

  // prologue: pa quads for kf0 + kf1
  bf16x8 pa0 = AF(0, 0), pa1 = AF(0, 1), pa2 = AF(0, 2), pa3 = AF(0, 3);
  bf16x8 pa4 = AF(1, 0), pa5 = AF(1, 1), pa6 = AF(1, 2), pa7 = AF(1, 3);

#define SCAN_STEP(S, RD, WR)                                                      \
  {                                                                               \
    const int s = (S);                                                            \
    f32x4 acc0 = {0,0,0,0}, acc1 = {0,0,0,0}, acc2 = {0,0,0,0}, acc3 = {0,0,0,0}; \
    /* prime depth-2 hb pipeline */                                               \
    bf16x8 hA = HB(0, RD);                                                        \
    bf16x8 hB = HB(1, RD);                                                        \
    /* kf0 (A=pa) */                                                              \
    acc0 = mfma16(pa0, hA, acc0); acc1 = mfma16(pa1, hA, acc1);                   \
    acc2 = mfma16(pa2, hA, acc2); acc3 = mfma16(pa3, hA, acc3);                   \
    hA = HB(2, RD);                                                               \
    /* kf1 (A=pa) */                                                              \
    acc0 = mfma16(pa4, hB, acc0); acc1 = mfma16(pa5, hB, acc1);                   \
    acc2 = mfma16(pa6, hB, acc2); acc3 = mfma16(pa7, hB, acc3);                   \
    hB = HB(3, RD);                                                               \
    /* kf2 (A from LDS) */                                                        \
    {                                                                             \
      const char* ab = smem + 2 * 32768 + apre;                                   \
      acc0 = mfma16(*reinterpret_cast<const bf16x8*>(ab       ), hA, acc0);       \
      acc1 = mfma16(*reinterpret_cast<const bf16x8*>(ab + 1024), hA, acc1);       \
      acc2 = mfma16(*reinterpret_cast<const bf16x8*>(ab + 2048), hA, acc2);       \
      acc3 = mfma16(*reinterpret_cast<const bf16x8*>(ab + 3072), hA, acc3);       \
    }                                                                             \
    hA = HB(4, RD);                                                               \
    /* kf3 (A from LDS) */                                                        \
    {                                                                             \
      const char* ab = smem + 3 * 32768 + apre;                                   \
      acc0 = mfma16(*reinterpret_cast<const bf16x8*>(ab       ), hB, acc0);       \
      acc1 = mfma16(*reinterpret_cast<const bf16x8*>(ab + 1024), hB, acc1);       \
      acc2 = mfma16(*reinterpret_cast<const bf16x8*>(ab + 2048), hB, acc2);       \
      acc3 = mfma16(*reinterpret_cast<const bf16x8*>(ab + 3072), hB, acc3);       \
    }                                                                             \
    hB = HB(5, RD);                                                               \
    /* xp(s): ~12 phases + epilogue of cover (HBM ~900 cyc) */                    \
    const float* xrs = xrow0 + (size_t)s * (64 * HID);                            \
    f32x4 xt0 = *reinterpret_cast<const f32x4*>(xrs);                             \
    f32x4 xt1 = *reinterpret_cast<const f32x4*>(xrs + 16);                        \
    f32x4 xt2 = *reinterpret_cast<const f32x4*>(xrs + 32);                        \
    f32x4 xt3 = *reinterpret_cast<const f32x4*>(xrs + 48);                        \
    /* kf4-15 (A from ar regs), alternating hA/hB with depth-2 refill */          \
    M4A(0, hA)  hA = HB(6, RD);                                                   \
    M4A(1, hB)  hB = HB(7, RD);                                                   \
    M4A(2, hA)  hA = HB(8, RD);                                                   \
    M4A(3, hB)  hB = HB(9, RD);                                                   \
    M4A(4, hA)  hA = HB(10, RD);                                                  \
    M4A(5, hB)  hB = HB(11, RD);                                                  \
    M4A(6, hA)  hA = HB(12, RD);                                                  \
    M4A(7, hB)  hB = HB(13, RD);                                                  \
    M4A(8, hA)  hA = HB(14, RD);                                                  \
    M4A(9, hB)  hB = HB(15, RD);                                                  \
    M4A(10, hA)                                                                   \
    M4A(11, hB)                                                                   \
    /* epilogue: tanh, f32x4 out, cvt_pk pack + uint2 h write */                  \
    float* orow = xrow0 + (size_t)s * (64 * HID);                                 \
    f32x4 hv0, hv1, hv2, hv3;                                                     \
    _Pragma("unroll")                                                             \
    for (int r = 0; r < 4; ++r) {                                                 \
      hv0[r] = 1.0f - 2.0f * __builtin_amdgcn_rcpf(1.0f + __expf(2.0f * (acc0[r] + xt0[r]))); \
      hv1[r] = 1.0f - 2.0f * __builtin_amdgcn_rcpf(1.0f + __expf(2.0f * (acc1[r] + xt1[r]))); \
      hv2[r] = 1.0f - 2.0f * __builtin_amdgcn_rcpf(1.0f + __expf(2.0f * (acc2[r] + xt2[r]))); \
      hv3[r] = 1.0f - 2.0f * __builtin_amdgcn_rcpf(1.0f + __expf(2.0f * (acc3[r] + xt3[r]))); \
    }                                                                             \
    *reinterpret_cast<f32x4*>(orow)      = hv0;                                   \
    *reinterpret_cast<f32x4*>(orow + 16) = hv1;                                   \
    *reinterpret_cast<f32x4*>(orow + 32) = hv2;                                   \
    *reinterpret_cast<f32x4*>(orow + 48) = hv3;                                   \
    uint2 hp;                                                                     \
    asm("v_cvt_pk_bf16_f32 %0, %1, %2" : "=v"(hp.x) : "v"(hv0[0]), "v"(hv0[1])); \
    asm("v_cvt_pk_bf16_f32 %0, %1, %2" : "=v"(hp.y) : "v"(hv0[2]), "v"(hv0[3])); \
    *reinterpret_cast<uint2*>(smem + 131072 + (WR) + hwb)        = hp;            \
    asm("v_cvt_pk_bf16_f32 %0, %1, %2" : "=v"(hp.x) : "v"(hv1[0]), "v"(hv1[1])); \
    asm("v_cvt_pk_bf16_f32 %0, %1, %2" : "=v"(hp.y) : "v"(hv1[2]), "v"(hv1[3])); \
    *reinterpret_cast<uint2*>(smem + 131072 + (WR) + hwb + 512)  = hp;            \
    asm("v_cvt_pk_bf16_f32 %0, %1, %2" : "=v"(hp.x) : "v"(hv2[0]), "v"(hv2[1])); \
    asm("v_cvt_pk_bf16_f32 %0, %1, %2" : "=v"(hp.y) : "v"(hv2[2]), "v"(hv2[3])); \
    *reinterpret_cast<uint2*>(smem + 131072 + (WR) + hwb + 1024) = hp;            \
    asm("v_cvt_pk_bf16_f32 %0, %1, %2" : "=v"(hp.x) : "v"(hv3[0]), "v"(hv3[1])); \
    asm("v_cvt_pk_bf16_f32 %0, %1, %2" : "=v"(hp.y) : "v"(hv3[2]), "v"(hv3[3])); \
    *reinterpret_cast<uint2*>(smem + 131072 + (WR) + hwb + 1536) = hp;            \
    /* pin order: h-writes above, pa reads below (keeps lgkmcnt(8) semantics) */  \
    __builtin_amdgcn_sched_barrier(0);                                            \
    pa0 = AF(0, 0); pa1 = AF(0, 1); pa2 = AF(0, 2); pa3 = AF(0, 3);               \
    pa4 = AF(1, 0); pa5 = AF(1, 1); pa6 = AF(1, 2); pa7 = AF(1, 3);               \
    /* counted: drain the 4 h-writes (older, in-order), keep 8 pa reads live */   \
    asm volatile("s_waitcnt lgkmcnt(8)\n\ts_barrier" ::: "memory");               \
  }

  #pragma unroll 1
  for (int s2 = 0; s2 < SEQ; s2 += 2) {
    SCAN_STEP(s2,     16384, 0)      // even step: read buf1, write buf0
    SCAN_STEP(s2 + 1, 0,     16384)  // odd step:  read buf0, write buf1
  }
#undef SCAN_STEP
#undef M4A
#undef HB
#undef AF
}

extern "C" void kernel_launch(void* const* d_in, const int* in_sizes, int n_in,
                              void* d_out, int out_size, void* d_ws, size_t ws_size,
                              hipStream_t stream) {
  (void)in_sizes; (void)n_in; (void)out_size;
  const float* X   = (const float*)d_in[0];
  const float* Wih = (const float*)d_in[1];
  const float* Whh = (const float*)d_in[2];
  const float* bih = (const float*)d_in[3];
  const float* bhh = (const float*)d_in[4];
  float* out = (float*)d_out;

  unsigned short* wihf = (unsigned short*)d_ws;              // 512 KB
  unsigned short* whhf = wihf + 262144;                      // 512 KB
  float* bsum = (float*)(whhf + 262144);                     // 2 KB
  if (ws_size < (size_t)(2 * 524288 + 2048)) return;

  prep_wfrag<<<1024, 256, 0, stream>>>(Wih, wihf);
  prep_wfrag<<<1024, 256, 0, stream>>>(Whh, whhf);
  prep_bsum<<<1, 512, 0, stream>>>(bih, bhh, bsum);

  rnn_xproj<<<2048, 512, 0, stream>>>(X, (const uint4*)wihf, bsum, out);

  hipFuncSetAttribute(reinterpret_cast<const void*>(rnn_scan),
                      hipFuncAttributeMaxDynamicSharedMemorySize, 163840);
  rnn_scan<<<4, 512, 163840, stream>>>((const uint4*)whhf, out);
}